// Round 7
// baseline (84.161 us; speedup 1.0000x reference)
//
#include <hip/hip_runtime.h>

// ResiduePose: coords[b,l,a,:] = R(q/|q|) · P[a] + (t[b,l] - mean_l t[b])
// B=32, L=65536, f32. Two kernels:
//   stage 1: partial sums; LAST block per batch (atomic counter) reduces the
//            64 partials -> 3-float mean (removes per-block mean work from pose)
//   stage 2: pose. quat load hoisted, 3-float mean read, LDS-staged output,
//            nontemporal coalesced stores.

#define BB 32
#define LL 65536
#define PB 64                             // partial-sum blocks per batch
#define RES_PER_BLOCK 256
#define POSE_BLOCKS ((BB * LL) / RES_PER_BLOCK)   // 8192

typedef float f32x4 __attribute__((ext_vector_type(4)));

// ---------------- stage 1: partial sums + last-block mean finalize ----------------
__global__ __launch_bounds__(256) void partial_sums_kernel(
    const f32x4* __restrict__ trans4, float* __restrict__ partials,
    float* __restrict__ means, unsigned int* __restrict__ counters) {
    const int bid = blockIdx.x;                  // = b*PB + p
    const int b = bid >> 6;                      // PB = 64
    const int tid = threadIdx.x;

    // one residue-group (4 residues = 3 f32x4 = 48 B) per thread, fully coalesced
    const size_t m = (size_t)bid * 768 + (size_t)tid * 3;
    const f32x4 a = trans4[m + 0];   // x0 y0 z0 x1
    const f32x4 c = trans4[m + 1];   // y1 z1 x2 y2
    const f32x4 d = trans4[m + 2];   // z2 x3 y3 z3
    float s0 = a.x + a.w + c.z + d.y;
    float s1 = a.y + c.x + c.w + d.z;
    float s2 = a.z + c.y + d.x + d.w;

#pragma unroll
    for (int off = 32; off > 0; off >>= 1) {
        s0 += __shfl_down(s0, off);
        s1 += __shfl_down(s1, off);
        s2 += __shfl_down(s2, off);
    }
    __shared__ float red[4][3];
    __shared__ bool last;
    const int wave = tid >> 6;
    if ((tid & 63) == 0) { red[wave][0] = s0; red[wave][1] = s1; red[wave][2] = s2; }
    __syncthreads();
    if (tid == 0) {
        float a0 = 0.f, a1 = 0.f, a2 = 0.f;
#pragma unroll
        for (int w = 0; w < 4; ++w) { a0 += red[w][0]; a1 += red[w][1]; a2 += red[w][2]; }
        partials[(size_t)bid * 3 + 0] = a0;
        partials[(size_t)bid * 3 + 1] = a1;
        partials[(size_t)bid * 3 + 2] = a2;
        __threadfence();                             // partials visible device-wide
        const unsigned int old = atomicAdd(&counters[b], 1u);   // device-scope
        last = (old == PB - 1);
    }
    __syncthreads();

    if (last) {                                      // block-uniform branch
        __shared__ float sp[PB * 3];
        if (tid < PB * 3) sp[tid] = partials[(size_t)b * (PB * 3) + tid];
        __syncthreads();
        if (tid < 3) {
            float s = 0.f;
#pragma unroll
            for (int p = 0; p < PB; ++p) s += sp[p * 3 + tid];
            means[b * 3 + tid] = s * (1.0f / (float)LL);
        }
    }
}

// ---------------- stage 2: pose, LDS-staged I/O, NT stores ----------------
__global__ __launch_bounds__(256) void pose_kernel(
    const f32x4* __restrict__ trans4, const f32x4* __restrict__ quat4,
    const float* __restrict__ means, f32x4* __restrict__ out4) {
    __shared__ f32x4 stage[768];     // 12 KB: trans staging, then output staging
    __shared__ float mean[3];

    const int tid = threadIdx.x;
    const int b = blockIdx.x >> 8;                      // 256 pose-blocks per batch
    const size_t r0 = (size_t)blockIdx.x * RES_PER_BLOCK;

    const f32x4 q4 = quat4[r0 + tid];                   // issue first: latency hides under staging
    if (tid < 192) stage[tid] = trans4[(size_t)blockIdx.x * 192 + tid];
    if (tid < 3) mean[tid] = means[b * 3 + tid];        // 3 scalar L2-broadcast loads
    __syncthreads();

    const float mx = mean[0], my = mean[1], mz = mean[2];
    const float* sf = (const float*)stage;              // stride-3 LDS reads: free
    const float tx = sf[tid * 3 + 0] - mx;
    const float ty = sf[tid * 3 + 1] - my;
    const float tz = sf[tid * 3 + 2] - mz;

    float r = q4.x, i = q4.y, j = q4.z, k = q4.w;
    const float inv = 1.0f / (sqrtf(r * r + i * i + j * j + k * k) + 1e-6f);
    r *= inv; i *= inv; j *= inv; k *= inv;

    const float R00 = 1.f - 2.f * (j * j + k * k);
    const float R01 = 2.f * (i * j - k * r);
    const float R02 = 2.f * (i * k + j * r);
    const float R10 = 2.f * (i * j + k * r);
    const float R11 = 1.f - 2.f * (i * i + k * k);
    const float R12 = 2.f * (j * k - i * r);
    const float R20 = 2.f * (i * k - j * r);
    const float R21 = 2.f * (j * k + i * r);
    const float R22 = 1.f - 2.f * (i * i + j * j);

    // idealized internal coords (N, CA=origin, C, CB)
    const float Nx = 1.460091f;
    const float Cx = -0.56431316f, Cy = 1.41695817f;
    const float Bx = -0.52426314f, By = -0.76611338f, Bz = 1.20561194f;

    const float N0 = R00 * Nx + tx, N1 = R10 * Nx + ty, N2 = R20 * Nx + tz;
    const float C0 = R00 * Cx + R01 * Cy + tx;
    const float C1 = R10 * Cx + R11 * Cy + ty;
    const float C2 = R20 * Cx + R21 * Cy + tz;
    const float B0 = R00 * Bx + R01 * By + R02 * Bz + tx;
    const float B1 = R10 * Bx + R11 * By + R12 * Bz + ty;
    const float B2 = R20 * Bx + R21 * By + R22 * Bz + tz;

    __syncthreads();   // done reading trans staging
    stage[tid * 3 + 0] = (f32x4){N0, N1, N2, tx};
    stage[tid * 3 + 1] = (f32x4){ty, tz, C0, C1};
    stage[tid * 3 + 2] = (f32x4){C2, B0, B1, B2};
    __syncthreads();

    // 3 lane-contiguous nontemporal f32x4 stores
    const size_t ob = r0 * 3;
    __builtin_nontemporal_store(stage[0 * 256 + tid], &out4[ob + 0 * 256 + tid]);
    __builtin_nontemporal_store(stage[1 * 256 + tid], &out4[ob + 1 * 256 + tid]);
    __builtin_nontemporal_store(stage[2 * 256 + tid], &out4[ob + 2 * 256 + tid]);
}

extern "C" void kernel_launch(void* const* d_in, const int* in_sizes, int n_in,
                              void* d_out, int out_size, void* d_ws, size_t ws_size,
                              hipStream_t stream) {
    const f32x4* trans4 = (const f32x4*)d_in[0];   // (B,L,3) f32
    const f32x4* quat4 = (const f32x4*)d_in[1];    // (B,L,4) f32
    f32x4* out4 = (f32x4*)d_out;                   // (B,L,4,3) f32

    float* partials = (float*)d_ws;                         // BB*PB*3 = 6144 floats
    float* means = partials + (size_t)BB * PB * 3;          // 96 floats
    unsigned int* counters = (unsigned int*)(means + BB * 3);   // 32 uints

    (void)hipMemsetAsync(counters, 0, BB * sizeof(unsigned int), stream);
    partial_sums_kernel<<<BB * PB, 256, 0, stream>>>(trans4, partials, means, counters);
    pose_kernel<<<POSE_BLOCKS, 256, 0, stream>>>(trans4, quat4, means, out4);
}

// Round 8
// 35.356 us; speedup vs baseline: 2.3804x; 2.3804x over previous
//
#include <hip/hip_runtime.h>

// ResiduePose: coords[b,l,a,:] = R(q/|q|) · P[a] + (t[b,l] - mean_l t[b])
// B=32, L=65536, f32.
//   stage 1: 128 fat blocks (1024 thr, 12 f32x4/thread) -> 4 partial sums/batch.
//            No atomics, no fences (r7 showed those cost 50+ us).
//   stage 2: pose (r7 structure, ~write-roofline): 3 lanes sum 4 partials ->
//            mean, LDS-staged trans + output, NT coalesced stores.

#define BB 32
#define LL 65536
#define S1_BLOCKS 128                     // 4 per batch
#define S1_TPB 1024
#define GROUPS_PER_S1_BLOCK 4096          // (LL/4) / 4
#define RES_PER_BLOCK 256
#define POSE_BLOCKS ((BB * LL) / RES_PER_BLOCK)   // 8192

typedef float f32x4 __attribute__((ext_vector_type(4)));

// ---------------- stage 1: partial sums, 128 x 1024 ----------------
__global__ __launch_bounds__(S1_TPB) void partial_sums_kernel(
    const f32x4* __restrict__ trans4, float* __restrict__ partials) {
    const int bid = blockIdx.x;
    const int tid = threadIdx.x;

    float s0 = 0.f, s1 = 0.f, s2 = 0.f;
#pragma unroll
    for (int k = 0; k < 4; ++k) {
        // group = 4 residues = 3 f32x4 = 48 B, one group per thread per k
        const size_t m = ((size_t)bid * GROUPS_PER_S1_BLOCK + k * S1_TPB + tid) * 3;
        const f32x4 a = trans4[m + 0];   // x0 y0 z0 x1
        const f32x4 c = trans4[m + 1];   // y1 z1 x2 y2
        const f32x4 d = trans4[m + 2];   // z2 x3 y3 z3
        s0 += a.x + a.w + c.z + d.y;
        s1 += a.y + c.x + c.w + d.z;
        s2 += a.z + c.y + d.x + d.w;
    }

#pragma unroll
    for (int off = 32; off > 0; off >>= 1) {
        s0 += __shfl_down(s0, off);
        s1 += __shfl_down(s1, off);
        s2 += __shfl_down(s2, off);
    }
    __shared__ float red[16][3];
    const int wave = tid >> 6;
    if ((tid & 63) == 0) { red[wave][0] = s0; red[wave][1] = s1; red[wave][2] = s2; }
    __syncthreads();
    if (tid < 3) {
        float s = 0.f;
#pragma unroll
        for (int w = 0; w < 16; ++w) s += red[w][tid];
        partials[bid * 3 + tid] = s;
    }
}

// ---------------- stage 2: pose, LDS-staged I/O, NT stores ----------------
__global__ __launch_bounds__(256) void pose_kernel(
    const f32x4* __restrict__ trans4, const f32x4* __restrict__ quat4,
    const float* __restrict__ partials, f32x4* __restrict__ out4) {
    __shared__ f32x4 stage[768];     // 12 KB: trans staging, then output staging
    __shared__ float mean[3];

    const int tid = threadIdx.x;
    const int b = blockIdx.x >> 8;                      // 256 pose-blocks per batch
    const size_t r0 = (size_t)blockIdx.x * RES_PER_BLOCK;

    const f32x4 q4 = quat4[r0 + tid];                   // issue first: hides under staging
    if (tid < 192) stage[tid] = trans4[(size_t)blockIdx.x * 192 + tid];
    if (tid < 3) {                                      // 4 L2-hit scalar loads + 3 adds
        mean[tid] = (partials[(b * 4 + 0) * 3 + tid] + partials[(b * 4 + 1) * 3 + tid] +
                     partials[(b * 4 + 2) * 3 + tid] + partials[(b * 4 + 3) * 3 + tid]) *
                    (1.0f / (float)LL);
    }
    __syncthreads();

    const float mx = mean[0], my = mean[1], mz = mean[2];
    const float* sf = (const float*)stage;              // stride-3 LDS reads: free
    const float tx = sf[tid * 3 + 0] - mx;
    const float ty = sf[tid * 3 + 1] - my;
    const float tz = sf[tid * 3 + 2] - mz;

    float r = q4.x, i = q4.y, j = q4.z, k = q4.w;
    const float inv = 1.0f / (sqrtf(r * r + i * i + j * j + k * k) + 1e-6f);
    r *= inv; i *= inv; j *= inv; k *= inv;

    const float R00 = 1.f - 2.f * (j * j + k * k);
    const float R01 = 2.f * (i * j - k * r);
    const float R02 = 2.f * (i * k + j * r);
    const float R10 = 2.f * (i * j + k * r);
    const float R11 = 1.f - 2.f * (i * i + k * k);
    const float R12 = 2.f * (j * k - i * r);
    const float R20 = 2.f * (i * k - j * r);
    const float R21 = 2.f * (j * k + i * r);
    const float R22 = 1.f - 2.f * (i * i + j * j);

    // idealized internal coords (N, CA=origin, C, CB)
    const float Nx = 1.460091f;
    const float Cx = -0.56431316f, Cy = 1.41695817f;
    const float Bx = -0.52426314f, By = -0.76611338f, Bz = 1.20561194f;

    const float N0 = R00 * Nx + tx, N1 = R10 * Nx + ty, N2 = R20 * Nx + tz;
    const float C0 = R00 * Cx + R01 * Cy + tx;
    const float C1 = R10 * Cx + R11 * Cy + ty;
    const float C2 = R20 * Cx + R21 * Cy + tz;
    const float B0 = R00 * Bx + R01 * By + R02 * Bz + tx;
    const float B1 = R10 * Bx + R11 * By + R12 * Bz + ty;
    const float B2 = R20 * Bx + R21 * By + R22 * Bz + tz;

    __syncthreads();   // done reading trans staging
    stage[tid * 3 + 0] = (f32x4){N0, N1, N2, tx};
    stage[tid * 3 + 1] = (f32x4){ty, tz, C0, C1};
    stage[tid * 3 + 2] = (f32x4){C2, B0, B1, B2};
    __syncthreads();

    // 3 lane-contiguous nontemporal f32x4 stores
    const size_t ob = r0 * 3;
    __builtin_nontemporal_store(stage[0 * 256 + tid], &out4[ob + 0 * 256 + tid]);
    __builtin_nontemporal_store(stage[1 * 256 + tid], &out4[ob + 1 * 256 + tid]);
    __builtin_nontemporal_store(stage[2 * 256 + tid], &out4[ob + 2 * 256 + tid]);
}

extern "C" void kernel_launch(void* const* d_in, const int* in_sizes, int n_in,
                              void* d_out, int out_size, void* d_ws, size_t ws_size,
                              hipStream_t stream) {
    const f32x4* trans4 = (const f32x4*)d_in[0];   // (B,L,3) f32
    const f32x4* quat4 = (const f32x4*)d_in[1];    // (B,L,4) f32
    f32x4* out4 = (f32x4*)d_out;                   // (B,L,4,3) f32

    float* partials = (float*)d_ws;                // S1_BLOCKS*3 = 384 floats

    partial_sums_kernel<<<S1_BLOCKS, S1_TPB, 0, stream>>>(trans4, partials);
    pose_kernel<<<POSE_BLOCKS, 256, 0, stream>>>(trans4, quat4, partials, out4);
}

// Round 9
// 34.459 us; speedup vs baseline: 2.4423x; 1.0260x over previous
//
#include <hip/hip_runtime.h>

// ResiduePose: coords[b,l,a,:] = R(q/|q|) · P[a] + (t[b,l] - mean_l t[b])
// B=32, L=65536, f32.
//   stage 1: 512 blocks x 512 threads (fills all 256 CUs), 2 groups/thread,
//            16 partials/batch. No atomics/fences (r7: those cost 50+ us).
//   stage 2: pose at write-roofline (r7 ~15.4 us): cheap 16-partial mean in
//            3 lanes, LDS-staged trans + output, NT coalesced stores.

#define BB 32
#define LL 65536
#define S1_BLOCKS 512                     // 16 per batch
#define S1_TPB 512
#define S1_GROUPS_PER_BLOCK 1024          // (BB*LL/4) / 512
#define RES_PER_BLOCK 256
#define POSE_BLOCKS ((BB * LL) / RES_PER_BLOCK)   // 8192
#define PPB 16                            // partials per batch

typedef float f32x4 __attribute__((ext_vector_type(4)));

// ---------------- stage 1: partial sums, 512 x 512 ----------------
__global__ __launch_bounds__(S1_TPB) void partial_sums_kernel(
    const f32x4* __restrict__ trans4, float* __restrict__ partials) {
    const int bid = blockIdx.x;
    const int tid = threadIdx.x;

    float s0 = 0.f, s1 = 0.f, s2 = 0.f;
#pragma unroll
    for (int it = 0; it < 2; ++it) {
        // group = 4 residues = 3 f32x4 = 48 B
        const size_t m = ((size_t)bid * S1_GROUPS_PER_BLOCK + it * S1_TPB + tid) * 3;
        const f32x4 a = trans4[m + 0];   // x0 y0 z0 x1
        const f32x4 c = trans4[m + 1];   // y1 z1 x2 y2
        const f32x4 d = trans4[m + 2];   // z2 x3 y3 z3
        s0 += a.x + a.w + c.z + d.y;
        s1 += a.y + c.x + c.w + d.z;
        s2 += a.z + c.y + d.x + d.w;
    }

#pragma unroll
    for (int off = 32; off > 0; off >>= 1) {
        s0 += __shfl_down(s0, off);
        s1 += __shfl_down(s1, off);
        s2 += __shfl_down(s2, off);
    }
    __shared__ float red[8][3];
    const int wave = tid >> 6;
    if ((tid & 63) == 0) { red[wave][0] = s0; red[wave][1] = s1; red[wave][2] = s2; }
    __syncthreads();
    if (tid < 3) {
        float s = 0.f;
#pragma unroll
        for (int w = 0; w < 8; ++w) s += red[w][tid];
        partials[bid * 3 + tid] = s;      // bid = b*PPB + p  (layout [b][16][3])
    }
}

// ---------------- stage 2: pose, LDS-staged I/O, NT stores ----------------
__global__ __launch_bounds__(256) void pose_kernel(
    const f32x4* __restrict__ trans4, const f32x4* __restrict__ quat4,
    const float* __restrict__ partials, f32x4* __restrict__ out4) {
    __shared__ f32x4 stage[768];     // 12 KB: trans staging, then output staging
    __shared__ float mean[3];

    const int tid = threadIdx.x;
    const int b = blockIdx.x >> 8;                      // 256 pose-blocks per batch
    const size_t r0 = (size_t)blockIdx.x * RES_PER_BLOCK;

    const f32x4 q4 = quat4[r0 + tid];                   // issue first: hides under staging
    if (tid < 192) stage[tid] = trans4[(size_t)blockIdx.x * 192 + tid];
    if (tid < 3) {                                      // 16 independent L2-hit loads, 1 wait
        float s = 0.f;
#pragma unroll
        for (int p = 0; p < PPB; ++p) s += partials[(b * PPB + p) * 3 + tid];
        mean[tid] = s * (1.0f / (float)LL);
    }
    __syncthreads();

    const float mx = mean[0], my = mean[1], mz = mean[2];
    const float* sf = (const float*)stage;              // stride-3 LDS reads: free
    const float tx = sf[tid * 3 + 0] - mx;
    const float ty = sf[tid * 3 + 1] - my;
    const float tz = sf[tid * 3 + 2] - mz;

    float r = q4.x, i = q4.y, j = q4.z, k = q4.w;
    const float inv = 1.0f / (sqrtf(r * r + i * i + j * j + k * k) + 1e-6f);
    r *= inv; i *= inv; j *= inv; k *= inv;

    const float R00 = 1.f - 2.f * (j * j + k * k);
    const float R01 = 2.f * (i * j - k * r);
    const float R02 = 2.f * (i * k + j * r);
    const float R10 = 2.f * (i * j + k * r);
    const float R11 = 1.f - 2.f * (i * i + k * k);
    const float R12 = 2.f * (j * k - i * r);
    const float R20 = 2.f * (i * k - j * r);
    const float R21 = 2.f * (j * k + i * r);
    const float R22 = 1.f - 2.f * (i * i + j * j);

    // idealized internal coords (N, CA=origin, C, CB)
    const float Nx = 1.460091f;
    const float Cx = -0.56431316f, Cy = 1.41695817f;
    const float Bx = -0.52426314f, By = -0.76611338f, Bz = 1.20561194f;

    const float N0 = R00 * Nx + tx, N1 = R10 * Nx + ty, N2 = R20 * Nx + tz;
    const float C0 = R00 * Cx + R01 * Cy + tx;
    const float C1 = R10 * Cx + R11 * Cy + ty;
    const float C2 = R20 * Cx + R21 * Cy + tz;
    const float B0 = R00 * Bx + R01 * By + R02 * Bz + tx;
    const float B1 = R10 * Bx + R11 * By + R12 * Bz + ty;
    const float B2 = R20 * Bx + R21 * By + R22 * Bz + tz;

    __syncthreads();   // done reading trans staging
    stage[tid * 3 + 0] = (f32x4){N0, N1, N2, tx};
    stage[tid * 3 + 1] = (f32x4){ty, tz, C0, C1};
    stage[tid * 3 + 2] = (f32x4){C2, B0, B1, B2};
    __syncthreads();

    // 3 lane-contiguous nontemporal f32x4 stores
    const size_t ob = r0 * 3;
    __builtin_nontemporal_store(stage[0 * 256 + tid], &out4[ob + 0 * 256 + tid]);
    __builtin_nontemporal_store(stage[1 * 256 + tid], &out4[ob + 1 * 256 + tid]);
    __builtin_nontemporal_store(stage[2 * 256 + tid], &out4[ob + 2 * 256 + tid]);
}

extern "C" void kernel_launch(void* const* d_in, const int* in_sizes, int n_in,
                              void* d_out, int out_size, void* d_ws, size_t ws_size,
                              hipStream_t stream) {
    const f32x4* trans4 = (const f32x4*)d_in[0];   // (B,L,3) f32
    const f32x4* quat4 = (const f32x4*)d_in[1];    // (B,L,4) f32
    f32x4* out4 = (f32x4*)d_out;                   // (B,L,4,3) f32

    float* partials = (float*)d_ws;                // S1_BLOCKS*3 = 1536 floats

    partial_sums_kernel<<<S1_BLOCKS, S1_TPB, 0, stream>>>(trans4, partials);
    pose_kernel<<<POSE_BLOCKS, 256, 0, stream>>>(trans4, quat4, partials, out4);
}